// Round 1
// baseline (340.815 us; speedup 1.0000x reference)
//
#include <hip/hip_runtime.h>

// Problem constants (match reference)
#define BATCH   4096
#define DIM     64
#define NTOT    (BATCH * DIM * DIM)   // 16,777,216 fp32 per tensor
#define NVEC    (NTOT / 4)            // 4,194,304 float4s
#define MRANK   32
#define GAMMA_C   0.1f
#define LAMBDA2_C 0.1f

#define THREADS 256
#define SBLOCKS 4096                  // streaming blocks
#define GRID    (SBLOCKS + 1)         // +1 dedicated trace block (block 0)
#define STRIDE  (SBLOCKS * THREADS)   // 1,048,576 float4s
#define ITERS   (NVEC / STRIDE)       // 4 — exact fit, no bounds checks

// Workspace layout (floats):
//   [0, SBLOCKS)              per-block sumsq partials
//   [SBLOCKS, SBLOCKS+32)     tr_pred[32]
//   [SBLOCKS+32, SBLOCKS+64)  tr_true[32]
//   at SBLOCKS+64             arrival counter (uint, memset to 0 each call)
// Total: 16,644 bytes.

// ---------------------------------------------------------------------------
// Fused single kernel, "last block finishes" pattern.
//  - Block 0: gathers the 32x2 diagonal traces (overlaps the stream).
//  - Blocks 1..SBLOCKS: each reduces 4 float4-pairs to one partial sumsq.
//  - Arrival: agent-scope release (threadfence) + device-scope atomicAdd on a
//    counter; the block seeing old == GRID-1 performs the finish: reduce 4096
//    partials, rank loss over the precomputed traces, write 3 outputs.
//  - Partials/traces use agent-scope atomic store/load so cross-XCD visibility
//    does not rely on L2 coherence (per-XCD L2s are not coherent).
// ---------------------------------------------------------------------------
__global__ void __launch_bounds__(THREADS, 4)
fused_loss_kernel(const float* __restrict__ pred, const float* __restrict__ tru,
                  float* __restrict__ ws, float* __restrict__ out)
{
    const int tid = threadIdx.x;
    const int bid = blockIdx.x;

    float* partials = ws;
    float* trp = ws + SBLOCKS;
    float* trt = ws + SBLOCKS + MRANK;
    unsigned int* cnt = (unsigned int*)(ws + SBLOCKS + 2 * MRANK);

    __shared__ float smem[THREADS / 64];
    __shared__ float red[2][THREADS];   // trace block only
    __shared__ float sp[MRANK], st[MRANK];
    __shared__ int   is_last;

    if (bid == 0) {
        // --- trace gather: 32 matrices x 64 diag elements, 8 per thread ---
        const int mat  = tid >> 3;   // 0..31
        const int part = tid & 7;    // 0..7
        float tp = 0.0f, tr = 0.0f;
        #pragma unroll
        for (int i = 0; i < 8; ++i) {
            const int j = part * 8 + i;
            const size_t off = (size_t)mat * (DIM * DIM) + (size_t)j * (DIM + 1);
            tp += pred[off];
            tr += tru[off];
        }
        red[0][tid] = tp;
        red[1][tid] = tr;
        __syncthreads();
        if (tid < MRANK) {
            float s1 = 0.0f, s2 = 0.0f;
            #pragma unroll
            for (int i = 0; i < 8; ++i) {
                s1 += red[0][tid * 8 + i];
                s2 += red[1][tid * 8 + i];
            }
            __hip_atomic_store(&trp[tid], s1, __ATOMIC_RELAXED, __HIP_MEMORY_SCOPE_AGENT);
            __hip_atomic_store(&trt[tid], s2, __ATOMIC_RELAXED, __HIP_MEMORY_SCOPE_AGENT);
        }
    } else {
        // --- streaming sumsq: 4 float4-pairs per thread, full preload ---
        const int g = (bid - 1) * THREADS + tid;
        const float4* __restrict__ p4 = (const float4*)pred;
        const float4* __restrict__ t4 = (const float4*)tru;
        float4 a[ITERS], b[ITERS];
        #pragma unroll
        for (int k = 0; k < ITERS; ++k) a[k] = p4[g + k * STRIDE];
        #pragma unroll
        for (int k = 0; k < ITERS; ++k) b[k] = t4[g + k * STRIDE];

        float acc = 0.0f;
        #pragma unroll
        for (int k = 0; k < ITERS; ++k) {
            const float dx = a[k].x - b[k].x;
            const float dy = a[k].y - b[k].y;
            const float dz = a[k].z - b[k].z;
            const float dw = a[k].w - b[k].w;
            acc += dx * dx + dy * dy + dz * dz + dw * dw;
        }
        #pragma unroll
        for (int off = 32; off > 0; off >>= 1)
            acc += __shfl_down(acc, off, 64);
        if ((tid & 63) == 0) smem[tid >> 6] = acc;
        __syncthreads();
        if (tid == 0)
            __hip_atomic_store(&partials[bid - 1],
                               smem[0] + smem[1] + smem[2] + smem[3],
                               __ATOMIC_RELAXED, __HIP_MEMORY_SCOPE_AGENT);
    }

    // --- arrival: release prior stores, bump device-scope counter ---
    __syncthreads();   // orders trace-block tid<32 stores before tid0's fence
    if (tid == 0) {
        __threadfence();                       // agent-scope release
        const unsigned int old = atomicAdd(cnt, 1u);   // device scope by default
        is_last = (old == (unsigned int)(GRID - 1)) ? 1 : 0;
    }
    __syncthreads();
    if (!is_last) return;

    // --- finish: exactly one block runs this ---
    __threadfence();                           // agent-scope acquire
    float s = 0.0f;
    #pragma unroll
    for (int k = 0; k < SBLOCKS / THREADS; ++k)
        s += __hip_atomic_load(&partials[tid + k * THREADS],
                               __ATOMIC_RELAXED, __HIP_MEMORY_SCOPE_AGENT);
    #pragma unroll
    for (int off = 32; off > 0; off >>= 1)
        s += __shfl_down(s, off, 64);
    if ((tid & 63) == 0) smem[tid >> 6] = s;   // safe: after __syncthreads above
    if (tid < MRANK) {
        sp[tid] = __hip_atomic_load(&trp[tid], __ATOMIC_RELAXED, __HIP_MEMORY_SCOPE_AGENT);
        st[tid] = __hip_atomic_load(&trt[tid], __ATOMIC_RELAXED, __HIP_MEMORY_SCOPE_AGENT);
    }
    __syncthreads();

    float racc = 0.0f;
    if (tid < MRANK) {
        const float pi = sp[tid];
        const float ti = st[tid];
        #pragma unroll
        for (int j = 0; j < MRANK; ++j) {
            if (j > tid) {
                const float dt = ti - st[j];
                const float dp = pi - sp[j];
                float c = 0.0f;
                if (dt > 0.0f)      c = fmaxf(-dp + GAMMA_C, 0.0f);
                else if (dt < 0.0f) c = fmaxf( dp + GAMMA_C, 0.0f);
                racc += c;
            }
        }
    }
    if (tid < 64) {
        #pragma unroll
        for (int off = 32; off > 0; off >>= 1)
            racc += __shfl_down(racc, off, 64);
        if (tid == 0) {
            const float total_ss = smem[0] + smem[1] + smem[2] + smem[3];
            const float eff  = total_ss / (float)NTOT;
            const float rank = racc / 496.0f;   // 32*31/2 pairs
            out[0] = eff + LAMBDA2_C * rank;
            out[1] = eff;
            out[2] = rank;
        }
    }
}

extern "C" void kernel_launch(void* const* d_in, const int* in_sizes, int n_in,
                              void* d_out, int out_size, void* d_ws, size_t ws_size,
                              hipStream_t stream) {
    const float* pred = (const float*)d_in[0];
    const float* tru  = (const float*)d_in[1];
    float* out = (float*)d_out;
    float* ws  = (float*)d_ws;

    // Arrival counter must be 0 every call (workspace may be poisoned between
    // iterations). 4-byte async memset is graph-capture-safe (stream op).
    unsigned int* cnt = (unsigned int*)(ws + SBLOCKS + 2 * MRANK);
    hipMemsetAsync(cnt, 0, sizeof(unsigned int), stream);

    fused_loss_kernel<<<GRID, THREADS, 0, stream>>>(pred, tru, ws, out);
}